// Round 11
// baseline (936.055 us; speedup 1.0000x reference)
//
#include <hip/hip_runtime.h>

#define HID 128
#define NR  16
#define NLAYER 4   // 3 hidden layers + output layer (transposed together)
#define CHUNK 32   // sorted edges per gather wave (was 16)
#define MAXN_LDS 20480
#define NXCD 8

__device__ __forceinline__ float dot4f(float4 a, float4 b) {
    return a.x * b.x + a.y * b.y + a.z * b.z + a.w * b.w;
}

// ---- K1: histogram of targets (4 edges/thread) + grid-stride zero of out ----
__global__ void hist_kernel(const int* __restrict__ eidx, int* __restrict__ hist,
                            float* __restrict__ out, int E, int n4) {
    const int gtid = blockIdx.x * blockDim.x + threadIdx.x;
    const int gstr = gridDim.x * blockDim.x;
    // zero the gather accumulator (runs before gather_kernel; safe)
    float4 z = make_float4(0.f, 0.f, 0.f, 0.f);
    float4* o4 = (float4*)out;
    for (int i = gtid; i < n4; i += gstr) o4[i] = z;

    int i = gtid * 4;
    if (i + 4 <= E) {
        int4 v = *(const int4*)(eidx + E + i);
        atomicAdd(&hist[v.x], 1);
        atomicAdd(&hist[v.y], 1);
        atomicAdd(&hist[v.z], 1);
        atomicAdd(&hist[v.w], 1);
    } else {
        for (; i < E; ++i) atomicAdd(&hist[eidx[E + i]], 1);
    }
}

// ---- K2: block 0 = exclusive scan (LDS-staged); blocks >=1 = weight transpose ----
__global__ __launch_bounds__(1024) void prep_kernel(const int* __restrict__ hist,
                                                    int* __restrict__ curs, int N,
                                                    const float* __restrict__ Ws,
                                                    const float* __restrict__ Wout,
                                                    float* __restrict__ WT) {
    const int tid = threadIdx.x;
    if (blockIdx.x > 0) {
        int idx = (blockIdx.x - 1) * 1024 + tid;
        if (idx < NLAYER * HID * HID) {
            int l = idx >> 14;
            int rem = idx & 16383;
            int h = rem >> 7, k = rem & 127;
            const float* src = (l < 3) ? (Ws + ((size_t)l << 14)) : Wout;
            WT[((size_t)l << 14) + (size_t)k * HID + h] = src[(size_t)h * HID + k];
        }
        return;
    }
    __shared__ int sh[MAXN_LDS];
    __shared__ int part[1024];
    const bool use_lds = (N <= MAXN_LDS);
    if (use_lds) {
        for (int i = tid; i < N; i += 1024) sh[i] = hist[i];
        __syncthreads();
    }
    const int per = (N + 1023) >> 10;
    const int base = tid * per;
    int s = 0;
    for (int i = 0; i < per; ++i) {
        int idx = base + i;
        if (idx < N) s += use_lds ? sh[idx] : hist[idx];
    }
    part[tid] = s;
    __syncthreads();
    for (int off = 1; off < 1024; off <<= 1) {
        int v = part[tid];
        int add = (tid >= off) ? part[tid - off] : 0;
        __syncthreads();
        part[tid] = v + add;
        __syncthreads();
    }
    int run = (tid > 0) ? part[tid - 1] : 0;
    for (int i = 0; i < per; ++i) {
        int idx = base + i;
        if (idx < N) {
            curs[idx] = run;
            run += use_lds ? sh[idx] : hist[idx];
        }
    }
}

// ---- K3: scatter {edge,target} pairs into sorted segments (4 edges/thread) ----
__global__ void scatter_kernel(const int* __restrict__ eidx, int* __restrict__ curs,
                               int2* __restrict__ pairs, int E) {
    int i = (blockIdx.x * blockDim.x + threadIdx.x) * 4;
    if (i + 4 <= E) {
        int4 v = *(const int4*)(eidx + E + i);
        int p;
        p = atomicAdd(&curs[v.x], 1); pairs[p] = make_int2(i + 0, v.x);
        p = atomicAdd(&curs[v.y], 1); pairs[p] = make_int2(i + 1, v.y);
        p = atomicAdd(&curs[v.z], 1); pairs[p] = make_int2(i + 2, v.z);
        p = atomicAdd(&curs[v.w], 1); pairs[p] = make_int2(i + 3, v.w);
    } else {
        for (; i < E; ++i) {
            int t = eidx[E + i];
            int p = atomicAdd(&curs[t], 1);
            pairs[p] = make_int2(i, t);
        }
    }
}

// ---- K4: edge-parallel gather, 32 sorted edges per wave, segmented flush ----
// Flat arrays only (R5/R9 lesson: struct/multi-phase bodies get spilled).
// ids/tg are wave-uniform -> SGPRs; VGPR budget ~115 (m[32]=64, wdh=32).
__global__ __launch_bounds__(256, 4) void gather_kernel(
    const float* __restrict__ dist, const float* __restrict__ msg,
    const float* __restrict__ Wd, const int2* __restrict__ pairs,
    float* __restrict__ node_emb, int E)
{
    __shared__ float sdist[4][CHUNK * NR];   // 2 KB per wave, wave-private

    // bijective XCD-chunked swizzle (m204)
    const int nwg = gridDim.x;
    const int q = nwg / NXCD, r = nwg % NXCD;
    const int xcd = blockIdx.x % NXCD, t = blockIdx.x / NXCD;
    const int bid = (xcd < r) ? (xcd * (q + 1) + t) : (r * (q + 1) + (xcd - r) * q + t);

    const int tid  = threadIdx.x;
    const int lane = tid & 63;
    const int wv   = tid >> 6;
    const long base = ((long)bid * 4 + wv) * CHUNK;
    if (base >= E) return;
    const int cnt = (E - base < CHUNK) ? (int)(E - base) : CHUNK;

    // half-row Wd fragments: lane pair covers 4 channels; kh = this lane's k-half
    const int base_ch = (lane >> 1) << 2;
    const int kh      = (lane & 1) * 8;
    float4 wdh[4][2];
#pragma unroll
    for (int j = 0; j < 4; ++j) {
        wdh[j][0] = *(const float4*)(Wd + (size_t)(base_ch + j) * NR + kh);
        wdh[j][1] = *(const float4*)(Wd + (size_t)(base_ch + j) * NR + kh + 4);
    }

    int ids[CHUNK], tg[CHUNK];
    if (cnt == CHUNK) {
#pragma unroll
        for (int q2 = 0; q2 < CHUNK / 2; ++q2) {   // int4 = 2 {edge,tgt} pairs
            int4 v = *(const int4*)(pairs + base + q2 * 2);
            ids[q2*2+0] = v.x; tg[q2*2+0] = v.y;
            ids[q2*2+1] = v.z; tg[q2*2+1] = v.w;
        }
    } else {
#pragma unroll
        for (int i = 0; i < CHUNK; ++i) {
            int2 v = (i < cnt) ? pairs[base + i] : make_int2(0, -1);
            ids[i] = v.x; tg[i] = v.y;
        }
    }

    // dist rows, coalesced: group g covers edges g*4..g*4+3; lane->(row,elem)
    float dv[CHUNK / 4];
#pragma unroll
    for (int g = 0; g < CHUNK / 4; ++g) {
        int e = ids[g * 4 + (lane >> 4)];
        dv[g] = dist[(size_t)e * NR + (lane & 15)];
    }

    // all msg loads issued together (16 KB per wave in flight)
    float2 m[CHUNK];
#pragma unroll
    for (int i = 0; i < CHUNK; ++i)
        m[i] = *(const float2*)(msg + (size_t)ids[i] * HID + 2 * lane);

    // stage dist rows into this wave's LDS region (wave-private, no barrier)
    float* sd = sdist[wv];
#pragma unroll
    for (int g = 0; g < CHUNK / 4; ++g)
        sd[g * 64 + lane] = dv[g];

    const bool odd = (lane & 1);
    float a0 = 0.f, a1 = 0.f;
#pragma unroll
    for (int i = 0; i < CHUNK; ++i) {
        if (i < cnt) {
            const float4* dr = (const float4*)(sd + i * NR + kh);  // broadcast
            float4 d0 = dr[0], d1 = dr[1];
            float p0 = dot4f(d0, wdh[0][0]) + dot4f(d1, wdh[0][1]);
            float p1 = dot4f(d0, wdh[1][0]) + dot4f(d1, wdh[1][1]);
            float p2 = dot4f(d0, wdh[2][0]) + dot4f(d1, wdh[2][1]);
            float p3 = dot4f(d0, wdh[3][0]) + dot4f(d1, wdh[3][1]);
            float s0 = odd ? p0 : p2;
            float s1 = odd ? p1 : p3;
            float r0 = __shfl_xor(s0, 1, 64);
            float r1 = __shfl_xor(s1, 1, 64);
            float g0 = (odd ? p2 : p0) + r0;
            float g1 = (odd ? p3 : p1) + r1;
            a0 += g0 * m[i].x;
            a1 += g1 * m[i].y;
            bool fl = (i == cnt - 1) || (tg[i + 1] != tg[i]);
            if (fl) {
                float* dst = node_emb + (size_t)tg[i] * HID + 2 * lane;
                unsafeAtomicAdd(dst,     a0);
                unsafeAtomicAdd(dst + 1, a1);
                a0 = 0.f; a1 = 0.f;
            }
        }
    }
}

// ---- K5: fused 3x(Linear+SiLU) + Linear out, 32-node tiles, XCD-swizzled ----
__global__ __launch_bounds__(256) void mlp_kernel(
    float* __restrict__ data, const float* __restrict__ WT,
    const float* __restrict__ bs, int N)
{
    __shared__ float xa[32][132];

    // bijective XCD swizzle: tile range aligns with gather's node ownership
    const int nwg = gridDim.x;
    const int q = nwg / NXCD, r = nwg % NXCD;
    const int xcd = blockIdx.x % NXCD, t = blockIdx.x / NXCD;
    const int bid = (xcd < r) ? (xcd * (q + 1) + t) : (r * (q + 1) + (xcd - r) * q + t);

    const int tid = threadIdx.x;
    const int nb  = bid * 32;
    const int hq  = tid & 31, h0 = hq * 4;
    const int nq  = tid >> 5, n0 = nq * 4;

    for (int i = tid; i < 32 * 32; i += 256) {
        int n = i >> 5, kq = i & 31;
        float4 v = make_float4(0.f, 0.f, 0.f, 0.f);
        if (nb + n < N) v = *(const float4*)(data + (size_t)(nb + n) * HID + kq * 4);
        *(float4*)(&xa[n][kq * 4]) = v;
    }
    __syncthreads();

    for (int l = 0; l < NLAYER; ++l) {
        const float* __restrict__ W = WT + ((size_t)l << 14);
        float acc[4][4];
        if (l < 3) {
            float b[4];
#pragma unroll
            for (int j = 0; j < 4; ++j) b[j] = bs[l * HID + h0 + j];
#pragma unroll
            for (int i = 0; i < 4; ++i)
#pragma unroll
                for (int j = 0; j < 4; ++j) acc[i][j] = b[j];
        } else {
#pragma unroll
            for (int i = 0; i < 4; ++i)
#pragma unroll
                for (int j = 0; j < 4; ++j) acc[i][j] = 0.f;
        }

        for (int k4 = 0; k4 < 32; ++k4) {
            float4 xv[4];
#pragma unroll
            for (int i = 0; i < 4; ++i) xv[i] = *(const float4*)(&xa[n0 + i][k4 * 4]);
            float4 wr[4];
#pragma unroll
            for (int kk = 0; kk < 4; ++kk)
                wr[kk] = *(const float4*)(W + (size_t)(k4 * 4 + kk) * HID + h0);
#pragma unroll
            for (int i = 0; i < 4; ++i) {
                acc[i][0] += xv[i].x * wr[0].x + xv[i].y * wr[1].x + xv[i].z * wr[2].x + xv[i].w * wr[3].x;
                acc[i][1] += xv[i].x * wr[0].y + xv[i].y * wr[1].y + xv[i].z * wr[2].y + xv[i].w * wr[3].y;
                acc[i][2] += xv[i].x * wr[0].z + xv[i].y * wr[1].z + xv[i].z * wr[2].z + xv[i].w * wr[3].z;
                acc[i][3] += xv[i].x * wr[0].w + xv[i].y * wr[1].w + xv[i].z * wr[2].w + xv[i].w * wr[3].w;
            }
        }
        __syncthreads();

        if (l < 3) {
#pragma unroll
            for (int i = 0; i < 4; ++i) {
                float4 y;
                y.x = acc[i][0] / (1.f + __expf(-acc[i][0]));
                y.y = acc[i][1] / (1.f + __expf(-acc[i][1]));
                y.z = acc[i][2] / (1.f + __expf(-acc[i][2]));
                y.w = acc[i][3] / (1.f + __expf(-acc[i][3]));
                *(float4*)(&xa[n0 + i][h0]) = y;
            }
            __syncthreads();
        } else {
#pragma unroll
            for (int i = 0; i < 4; ++i) {
                if (nb + n0 + i < N) {
                    float4 y = make_float4(acc[i][0], acc[i][1], acc[i][2], acc[i][3]);
                    *(float4*)(data + (size_t)(nb + n0 + i) * HID + h0) = y;
                }
            }
        }
    }
}

extern "C" void kernel_launch(void* const* d_in, const int* in_sizes, int n_in,
                              void* d_out, int out_size, void* d_ws, size_t ws_size,
                              hipStream_t stream) {
    const float* dist = (const float*)d_in[0];
    const float* msg  = (const float*)d_in[1];
    const int*   eidx = (const int*)d_in[2];
    const float* Wd   = (const float*)d_in[4];
    const float* Ws   = (const float*)d_in[5];
    const float* bs   = (const float*)d_in[6];
    const float* Wout = (const float*)d_in[7];
    float* out = (float*)d_out;

    const int E = in_sizes[1] / HID;
    const int N = out_size / HID;

    // ws layout (4-byte elems; pairs 16 B-aligned for int4 loads)
    int*   hist   = (int*)d_ws;                       // [N]
    int*   curs   = hist + N;                         // [N]
    size_t pr_off = ((size_t)(2 * N) + 3) & ~(size_t)3;
    int2*  pairs  = (int2*)((int*)d_ws + pr_off);     // [E] {edge,tgt}
    size_t wt_off = (pr_off + (size_t)2 * E + 3) & ~(size_t)3;
    float* WT     = (float*)d_ws + wt_off;            // [4*128*128]

    hipMemsetAsync(hist, 0, (size_t)N * sizeof(int), stream);

    const int qE = (E + 3) / 4;
    const int tblocks = (NLAYER * HID * HID + 1023) / 1024;
    hist_kernel   <<<(qE + 255) / 256, 256, 0, stream>>>(eidx, hist, out, E, N * HID / 4);
    prep_kernel   <<<1 + tblocks, 1024, 0, stream>>>(hist, curs, N, Ws, Wout, WT);
    scatter_kernel<<<(qE + 255) / 256, 256, 0, stream>>>(eidx, curs, pairs, E);

    const long waves = ((long)E + CHUNK - 1) / CHUNK;
    gather_kernel <<<(int)((waves + 3) / 4), 256, 0, stream>>>(dist, msg, Wd, pairs, out, E);
    mlp_kernel    <<<(N + 31) / 32, 256, 0, stream>>>(out, WT, bs, N);
}

// Round 12
// 256.041 us; speedup vs baseline: 3.6559x; 3.6559x over previous
//
#include <hip/hip_runtime.h>

#define HID 128
#define NR  16
#define NLAYER 4   // 3 hidden layers + output layer (transposed together)
#define CHUNK 16   // sorted edges per gather wave — PROVEN register-resident cap
#define MAXN_LDS 20480
#define NXCD 8

__device__ __forceinline__ float dot4f(float4 a, float4 b) {
    return a.x * b.x + a.y * b.y + a.z * b.z + a.w * b.w;
}

// ---- K1: histogram of targets (4 edges/thread) + grid-stride zero of out ----
__global__ void hist_kernel(const int* __restrict__ eidx, int* __restrict__ hist,
                            float* __restrict__ out, int E, int n4) {
    const int gtid = blockIdx.x * blockDim.x + threadIdx.x;
    const int gstr = gridDim.x * blockDim.x;
    float4 z = make_float4(0.f, 0.f, 0.f, 0.f);
    float4* o4 = (float4*)out;
    for (int i = gtid; i < n4; i += gstr) o4[i] = z;

    int i = gtid * 4;
    if (i + 4 <= E) {
        int4 v = *(const int4*)(eidx + E + i);
        atomicAdd(&hist[v.x], 1);
        atomicAdd(&hist[v.y], 1);
        atomicAdd(&hist[v.z], 1);
        atomicAdd(&hist[v.w], 1);
    } else {
        for (; i < E; ++i) atomicAdd(&hist[eidx[E + i]], 1);
    }
}

// ---- K2: block 0 = exclusive scan (LDS-staged); blocks >=1 = weight transpose ----
__global__ __launch_bounds__(1024) void prep_kernel(const int* __restrict__ hist,
                                                    int* __restrict__ curs, int N,
                                                    const float* __restrict__ Ws,
                                                    const float* __restrict__ Wout,
                                                    float* __restrict__ WT) {
    const int tid = threadIdx.x;
    if (blockIdx.x > 0) {
        int idx = (blockIdx.x - 1) * 1024 + tid;
        if (idx < NLAYER * HID * HID) {
            int l = idx >> 14;
            int rem = idx & 16383;
            int h = rem >> 7, k = rem & 127;
            const float* src = (l < 3) ? (Ws + ((size_t)l << 14)) : Wout;
            WT[((size_t)l << 14) + (size_t)k * HID + h] = src[(size_t)h * HID + k];
        }
        return;
    }
    __shared__ int sh[MAXN_LDS];
    __shared__ int part[1024];
    const bool use_lds = (N <= MAXN_LDS);
    if (use_lds) {
        for (int i = tid; i < N; i += 1024) sh[i] = hist[i];
        __syncthreads();
    }
    const int per = (N + 1023) >> 10;
    const int base = tid * per;
    int s = 0;
    for (int i = 0; i < per; ++i) {
        int idx = base + i;
        if (idx < N) s += use_lds ? sh[idx] : hist[idx];
    }
    part[tid] = s;
    __syncthreads();
    for (int off = 1; off < 1024; off <<= 1) {
        int v = part[tid];
        int add = (tid >= off) ? part[tid - off] : 0;
        __syncthreads();
        part[tid] = v + add;
        __syncthreads();
    }
    int run = (tid > 0) ? part[tid - 1] : 0;
    for (int i = 0; i < per; ++i) {
        int idx = base + i;
        if (idx < N) {
            curs[idx] = run;
            run += use_lds ? sh[idx] : hist[idx];
        }
    }
}

// ---- K3: scatter {edge,target} pairs into sorted segments (4 edges/thread) ----
__global__ void scatter_kernel(const int* __restrict__ eidx, int* __restrict__ curs,
                               int2* __restrict__ pairs, int E) {
    int i = (blockIdx.x * blockDim.x + threadIdx.x) * 4;
    if (i + 4 <= E) {
        int4 v = *(const int4*)(eidx + E + i);
        int p;
        p = atomicAdd(&curs[v.x], 1); pairs[p] = make_int2(i + 0, v.x);
        p = atomicAdd(&curs[v.y], 1); pairs[p] = make_int2(i + 1, v.y);
        p = atomicAdd(&curs[v.z], 1); pairs[p] = make_int2(i + 2, v.z);
        p = atomicAdd(&curs[v.w], 1); pairs[p] = make_int2(i + 3, v.w);
    } else {
        for (; i < E; ++i) {
            int t = eidx[E + i];
            int p = atomicAdd(&curs[t], 1);
            pairs[p] = make_int2(i, t);
        }
    }
}

// ---- K4: edge-parallel gather, 16 sorted edges per wave, segmented flush ----
// R6-proven body: register-resident (VGPR ~80), no LDS conflicts.
__global__ __launch_bounds__(256, 4) void gather_kernel(
    const float* __restrict__ dist, const float* __restrict__ msg,
    const float* __restrict__ Wd, const int2* __restrict__ pairs,
    float* __restrict__ node_emb, int E)
{
    __shared__ float sdist[4][CHUNK * NR];   // 1 KB per wave, wave-private

    // bijective XCD-chunked swizzle (m204)
    const int nwg = gridDim.x;
    const int q = nwg / NXCD, r = nwg % NXCD;
    const int xcd = blockIdx.x % NXCD, t = blockIdx.x / NXCD;
    const int bid = (xcd < r) ? (xcd * (q + 1) + t) : (r * (q + 1) + (xcd - r) * q + t);

    const int tid  = threadIdx.x;
    const int lane = tid & 63;
    const int wv   = tid >> 6;
    const long base = ((long)bid * 4 + wv) * CHUNK;
    if (base >= E) return;
    const int cnt = (E - base < CHUNK) ? (int)(E - base) : CHUNK;

    const int base_ch = (lane >> 1) << 2;
    const int kh      = (lane & 1) * 8;
    float4 wdh[4][2];
#pragma unroll
    for (int j = 0; j < 4; ++j) {
        wdh[j][0] = *(const float4*)(Wd + (size_t)(base_ch + j) * NR + kh);
        wdh[j][1] = *(const float4*)(Wd + (size_t)(base_ch + j) * NR + kh + 4);
    }

    int ids[CHUNK], tg[CHUNK];
    if (cnt == CHUNK) {
#pragma unroll
        for (int q2 = 0; q2 < CHUNK / 2; ++q2) {
            int4 v = *(const int4*)(pairs + base + q2 * 2);
            ids[q2*2+0] = v.x; tg[q2*2+0] = v.y;
            ids[q2*2+1] = v.z; tg[q2*2+1] = v.w;
        }
    } else {
#pragma unroll
        for (int i = 0; i < CHUNK; ++i) {
            int2 v = (i < cnt) ? pairs[base + i] : make_int2(0, -1);
            ids[i] = v.x; tg[i] = v.y;
        }
    }

    float dv[CHUNK / 4];
#pragma unroll
    for (int g = 0; g < CHUNK / 4; ++g) {
        int e = ids[g * 4 + (lane >> 4)];
        dv[g] = dist[(size_t)e * NR + (lane & 15)];
    }

    float2 m[CHUNK];
#pragma unroll
    for (int i = 0; i < CHUNK; ++i)
        m[i] = *(const float2*)(msg + (size_t)ids[i] * HID + 2 * lane);

    float* sd = sdist[wv];
#pragma unroll
    for (int g = 0; g < CHUNK / 4; ++g)
        sd[g * 64 + lane] = dv[g];

    const bool odd = (lane & 1);
    float a0 = 0.f, a1 = 0.f;
#pragma unroll
    for (int i = 0; i < CHUNK; ++i) {
        if (i < cnt) {
            const float4* dr = (const float4*)(sd + i * NR + kh);
            float4 d0 = dr[0], d1 = dr[1];
            float p0 = dot4f(d0, wdh[0][0]) + dot4f(d1, wdh[0][1]);
            float p1 = dot4f(d0, wdh[1][0]) + dot4f(d1, wdh[1][1]);
            float p2 = dot4f(d0, wdh[2][0]) + dot4f(d1, wdh[2][1]);
            float p3 = dot4f(d0, wdh[3][0]) + dot4f(d1, wdh[3][1]);
            float s0 = odd ? p0 : p2;
            float s1 = odd ? p1 : p3;
            float r0 = __shfl_xor(s0, 1, 64);
            float r1 = __shfl_xor(s1, 1, 64);
            float g0 = (odd ? p2 : p0) + r0;
            float g1 = (odd ? p3 : p1) + r1;
            a0 += g0 * m[i].x;
            a1 += g1 * m[i].y;
            bool fl = (i == cnt - 1) || (tg[i + 1] != tg[i]);
            if (fl) {
                float* dst = node_emb + (size_t)tg[i] * HID + 2 * lane;
                unsafeAtomicAdd(dst,     a0);
                unsafeAtomicAdd(dst + 1, a1);
                a0 = 0.f; a1 = 0.f;
            }
        }
    }
}

// ---- K5: fused 3x(Linear+SiLU) + Linear out, 32-node tiles, XCD-swizzled ----
__global__ __launch_bounds__(256) void mlp_kernel(
    float* __restrict__ data, const float* __restrict__ WT,
    const float* __restrict__ bs, int N)
{
    __shared__ float xa[32][132];

    const int nwg = gridDim.x;
    const int q = nwg / NXCD, r = nwg % NXCD;
    const int xcd = blockIdx.x % NXCD, t = blockIdx.x / NXCD;
    const int bid = (xcd < r) ? (xcd * (q + 1) + t) : (r * (q + 1) + (xcd - r) * q + t);

    const int tid = threadIdx.x;
    const int nb  = bid * 32;
    const int hq  = tid & 31, h0 = hq * 4;
    const int nq  = tid >> 5, n0 = nq * 4;

    for (int i = tid; i < 32 * 32; i += 256) {
        int n = i >> 5, kq = i & 31;
        float4 v = make_float4(0.f, 0.f, 0.f, 0.f);
        if (nb + n < N) v = *(const float4*)(data + (size_t)(nb + n) * HID + kq * 4);
        *(float4*)(&xa[n][kq * 4]) = v;
    }
    __syncthreads();

    for (int l = 0; l < NLAYER; ++l) {
        const float* __restrict__ W = WT + ((size_t)l << 14);
        float acc[4][4];
        if (l < 3) {
            float b[4];
#pragma unroll
            for (int j = 0; j < 4; ++j) b[j] = bs[l * HID + h0 + j];
#pragma unroll
            for (int i = 0; i < 4; ++i)
#pragma unroll
                for (int j = 0; j < 4; ++j) acc[i][j] = b[j];
        } else {
#pragma unroll
            for (int i = 0; i < 4; ++i)
#pragma unroll
                for (int j = 0; j < 4; ++j) acc[i][j] = 0.f;
        }

        for (int k4 = 0; k4 < 32; ++k4) {
            float4 xv[4];
#pragma unroll
            for (int i = 0; i < 4; ++i) xv[i] = *(const float4*)(&xa[n0 + i][k4 * 4]);
            float4 wr[4];
#pragma unroll
            for (int kk = 0; kk < 4; ++kk)
                wr[kk] = *(const float4*)(W + (size_t)(k4 * 4 + kk) * HID + h0);
#pragma unroll
            for (int i = 0; i < 4; ++i) {
                acc[i][0] += xv[i].x * wr[0].x + xv[i].y * wr[1].x + xv[i].z * wr[2].x + xv[i].w * wr[3].x;
                acc[i][1] += xv[i].x * wr[0].y + xv[i].y * wr[1].y + xv[i].z * wr[2].y + xv[i].w * wr[3].y;
                acc[i][2] += xv[i].x * wr[0].z + xv[i].y * wr[1].z + xv[i].z * wr[2].z + xv[i].w * wr[3].z;
                acc[i][3] += xv[i].x * wr[0].w + xv[i].y * wr[1].w + xv[i].z * wr[2].w + xv[i].w * wr[3].w;
            }
        }
        __syncthreads();

        if (l < 3) {
#pragma unroll
            for (int i = 0; i < 4; ++i) {
                float4 y;
                y.x = acc[i][0] / (1.f + __expf(-acc[i][0]));
                y.y = acc[i][1] / (1.f + __expf(-acc[i][1]));
                y.z = acc[i][2] / (1.f + __expf(-acc[i][2]));
                y.w = acc[i][3] / (1.f + __expf(-acc[i][3]));
                *(float4*)(&xa[n0 + i][h0]) = y;
            }
            __syncthreads();
        } else {
#pragma unroll
            for (int i = 0; i < 4; ++i) {
                if (nb + n0 + i < N) {
                    float4 y = make_float4(acc[i][0], acc[i][1], acc[i][2], acc[i][3]);
                    *(float4*)(data + (size_t)(nb + n0 + i) * HID + h0) = y;
                }
            }
        }
    }
}

extern "C" void kernel_launch(void* const* d_in, const int* in_sizes, int n_in,
                              void* d_out, int out_size, void* d_ws, size_t ws_size,
                              hipStream_t stream) {
    const float* dist = (const float*)d_in[0];
    const float* msg  = (const float*)d_in[1];
    const int*   eidx = (const int*)d_in[2];
    const float* Wd   = (const float*)d_in[4];
    const float* Ws   = (const float*)d_in[5];
    const float* bs   = (const float*)d_in[6];
    const float* Wout = (const float*)d_in[7];
    float* out = (float*)d_out;

    const int E = in_sizes[1] / HID;
    const int N = out_size / HID;

    int*   hist   = (int*)d_ws;                       // [N]
    int*   curs   = hist + N;                         // [N]
    size_t pr_off = ((size_t)(2 * N) + 3) & ~(size_t)3;
    int2*  pairs  = (int2*)((int*)d_ws + pr_off);     // [E] {edge,tgt}
    size_t wt_off = (pr_off + (size_t)2 * E + 3) & ~(size_t)3;
    float* WT     = (float*)d_ws + wt_off;            // [4*128*128]

    hipMemsetAsync(hist, 0, (size_t)N * sizeof(int), stream);

    const int qE = (E + 3) / 4;
    const int tblocks = (NLAYER * HID * HID + 1023) / 1024;
    hist_kernel   <<<(qE + 255) / 256, 256, 0, stream>>>(eidx, hist, out, E, N * HID / 4);
    prep_kernel   <<<1 + tblocks, 1024, 0, stream>>>(hist, curs, N, Ws, Wout, WT);
    scatter_kernel<<<(qE + 255) / 256, 256, 0, stream>>>(eidx, curs, pairs, E);

    const long waves = ((long)E + CHUNK - 1) / CHUNK;
    gather_kernel <<<(int)((waves + 3) / 4), 256, 0, stream>>>(dist, msg, Wd, pairs, out, E);
    mlp_kernel    <<<(N + 31) / 32, 256, 0, stream>>>(out, WT, bs, N);
}